// Round 7
// baseline (108.289 us; speedup 1.0000x reference)
//
#include <hip/hip_runtime.h>
#include <hip/hip_bf16.h>
#include <math.h>

#define H_    12
#define B_    2
#define N_    512
#define BH_   (B_*H_)
#define QSCALE 0.14433756729740643f          // 1/sqrt(48)
#define CPT_K  0.13608276348795434f          // sqrt(1/54)

// ---------------- ws layout (float units) ----------------
#define OFF_QB   1356928                     // bf16 [bh][512][32]
#define OFF_KP   1553536                     // bf16 [bh][32jt][4kq][16j][8]
#define OFF_VP   1750144                     // bf16 [bh][16jt32][3nq][4kq][16n][8j]
#define OFF_SA   2045056                     // f32 [bh*512]
#define OFF_SB   2057344                     // f32 [bh*512]
#define OFF_CATP 2069632                     // bf16 [64mt][18ks][4kq][16m][8]

typedef __attribute__((ext_vector_type(8))) short sh8;
typedef __attribute__((ext_vector_type(4))) float f32x4;
typedef unsigned short u16t;

static __device__ __forceinline__ u16t f2b(float x) {
    __hip_bfloat16 h = __float2bfloat16(x);
    return *reinterpret_cast<u16t*>(&h);
}
static __device__ __forceinline__ int catp_idx(int tok, int col) {
    return (tok >> 4)*9216 + (col >> 5)*512 + ((col >> 3) & 3)*128
         + (tok & 15)*8 + (col & 7);
}

// ---------------------------------------------------------------------------
// Kernel 1: fused proj GEMM + rotation + bf16 pack, half-column split.
// Grid 256 (= 1 block/CU): bid>>1 = 8-token group, bid&1 = column half.
// (unchanged from R5)
// ---------------------------------------------------------------------------
__global__ __launch_bounds__(512) void projpack_kernel(
    const float* __restrict__ s,
    const float* __restrict__ Rg, const float* __restrict__ tg,
    const float* __restrict__ hwg,
    const float* __restrict__ Wq,  const float* __restrict__ bq,
    const float* __restrict__ Wkv, const float* __restrict__ bkv,
    const float* __restrict__ Wqp, const float* __restrict__ bqp,
    const float* __restrict__ Wkvp,const float* __restrict__ bkvp,
    float* __restrict__ ws)
{
    __shared__ float ldsP[8][1160];   // 8 tokens x 1152 (+8 pad); half-used/block

    u16t* Qb = (u16t*)(ws + OFF_QB);
    u16t* Kp = (u16t*)(ws + OFF_KP);
    u16t* Vp = (u16t*)(ws + OFF_VP);
    float* sa_g = ws + OFF_SA;
    float* sb_g = ws + OFF_SB;

    const int tid  = threadIdx.x;
    const int w    = tid >> 6, lane = tid & 63;
    const int kq   = lane >> 4, lx = lane & 15;
    const int half = blockIdx.x & 1;
    const int tok0 = (blockIdx.x >> 1) * 8;
    const int b    = tok0 >> 9, n0 = tok0 & 511;

    // A-frags: s rows tok0 + (lx&7), k = ks*32 + kq*8 .. +8
    sh8 afr[4];
    #pragma unroll
    for (int ks = 0; ks < 4; ++ks) {
        const float* src = s + (tok0 + (lx & 7))*128 + ks*32 + kq*8;
        float4 u0 = *(const float4*)(src);
        float4 u1 = *(const float4*)(src+4);
        union { sh8 v; u16t u[8]; } pk;
        pk.u[0]=f2b(u0.x); pk.u[1]=f2b(u0.y); pk.u[2]=f2b(u0.z); pk.u[3]=f2b(u0.w);
        pk.u[4]=f2b(u1.x); pk.u[5]=f2b(u1.y); pk.u[6]=f2b(u1.z); pk.u[7]=f2b(u1.w);
        afr[ks] = pk.v;
    }

    const int gstart = (w < 4) ? w*5 : 20 + (w-4)*4;
    const int ng     = (w < 4) ? 5 : 4;

    for (int g = 0; g < ng; ++g) {
        int gg  = half*36 + gstart + g;    // global col-group 0..71
        int col = gg*16 + lx;              // each 16-col group maps to ONE matrix
        const float* wsrc; int lc, od; float bv;
        if (col < 192)      { wsrc = Wq;   lc = col;     od = 192; bv = bq[lc]; }
        else if (col < 576) { wsrc = Wkv;  lc = col-192; od = 384; bv = bkv[lc]; }
        else if (col < 720) { wsrc = Wqp;  lc = col-576; od = 144; bv = bqp[lc]; }
        else                { wsrc = Wkvp; lc = col-720; od = 432; bv = bkvp[lc]; }

        f32x4 acc = {0.f,0.f,0.f,0.f};
        #pragma unroll
        for (int ks = 0; ks < 4; ++ks) {
            int k0 = ks*32 + kq*8;
            union { sh8 v; u16t u[8]; } pk;
            #pragma unroll
            for (int j = 0; j < 8; ++j) pk.u[j] = f2b(wsrc[(k0+j)*od + lc]);
            acc = __builtin_amdgcn_mfma_f32_16x16x32_bf16(afr[ks], pk.v, acc, 0, 0, 0);
        }
        if (kq < 2) {                      // C rows 0..7 only
            #pragma unroll
            for (int r = 0; r < 4; ++r)
                ldsP[kq*4 + r][gg*16 + lx] = acc[r] + bv;
        }
    }
    __syncthreads();

    if (half == 1) {
        // in-place rotation: qp (cols 576..720)
        for (int idx = tid; idx < 8*48; idx += 512) {
            int tk = idx / 48, p = idx % 48;
            int tok = tok0 + tk;
            const float* Rr = Rg + tok*9;
            const float* tr = tg + tok*3;
            float x0 = ldsP[tk][576 +  0 + p];
            float x1 = ldsP[tk][576 + 48 + p];
            float x2 = ldsP[tk][576 + 96 + p];
            ldsP[tk][576 +  0 + p] = Rr[0]*x0 + Rr[1]*x1 + Rr[2]*x2 + tr[0];
            ldsP[tk][576 + 48 + p] = Rr[3]*x0 + Rr[4]*x1 + Rr[5]*x2 + tr[1];
            ldsP[tk][576 + 96 + p] = Rr[6]*x0 + Rr[7]*x1 + Rr[8]*x2 + tr[2];
        }
        // in-place rotation: kvp (cols 720..1152)
        for (int idx = tid; idx < 8*144; idx += 512) {
            int tk = idx / 144, p = idx % 144;
            int tok = tok0 + tk;
            const float* Rr = Rg + tok*9;
            const float* tr = tg + tok*3;
            float x0 = ldsP[tk][720 +   0 + p];
            float x1 = ldsP[tk][720 + 144 + p];
            float x2 = ldsP[tk][720 + 288 + p];
            ldsP[tk][720 +   0 + p] = Rr[0]*x0 + Rr[1]*x1 + Rr[2]*x2 + tr[0];
            ldsP[tk][720 + 144 + p] = Rr[3]*x0 + Rr[4]*x1 + Rr[5]*x2 + tr[1];
            ldsP[tk][720 + 288 + p] = Rr[6]*x0 + Rr[7]*x1 + Rr[8]*x2 + tr[2];
        }
        __syncthreads();

        // Qb half1 (point part): tasks (tk,h)
        for (int idx = tid; idx < 8*12; idx += 512) {
            int tk = idx / 12, h = idx % 12;
            float hx = hwg[h];
            float sp = (hx > 20.f) ? hx : log1pf(__expf(hx));
            float qs = sp * CPT_K;         // = -2 * c_pt
            union { sh8 v[2]; u16t u[16]; } pk;
            #pragma unroll
            for (int e = 0; e < 12; ++e)
                pk.u[e] = f2b(ldsP[tk][576 + (e%3)*48 + h*4 + e/3] * qs);
            pk.u[12]=0; pk.u[13]=0; pk.u[14]=0; pk.u[15]=0;
            u16t* dst = Qb + ((b*H_+h)*N_ + n0 + tk)*32 + 16;
            *(sh8*)dst = pk.v[0];
            *(sh8*)(dst+8) = pk.v[1];
        }
        // Kp point frags fq in {2,3}: tasks (tk,h,fq)
        for (int idx = tid; idx < 8*24; idx += 512) {
            int tk = idx / 24, r2 = idx % 24, h = r2 >> 1, fq = 2 + (r2 & 1);
            int j = n0 + tk, bh = b*H_ + h;
            union { sh8 v; u16t u[8]; } pk;
            #pragma unroll
            for (int e = 0; e < 8; ++e) {
                int c = fq*8 + e;
                float val;
                if (c < 28) val = ldsP[tk][720 + ((c-16)%3)*144 + h*12 + (c-16)/3];
                else        val = 0.f;
                pk.u[e] = f2b(val);
            }
            *(sh8*)(Kp + bh*16384 + (j>>4)*512 + fq*128 + (j&15)*8) = pk.v;
        }
        // Vp point frags d in [16,40): tasks (h,d-16)
        for (int idx = tid; idx < 12*24; idx += 512) {
            int h = idx / 24, d = 16 + idx % 24;
            int bh = b*H_ + h;
            union { sh8 v; u16t u[8]; } pk;
            #pragma unroll
            for (int e = 0; e < 8; ++e)
                pk.u[e] = f2b(ldsP[e][720 + ((d-16)%3)*144 + h*12 + 4 + (d-16)/3]);
            int j = n0;
            *(sh8*)(Vp + bh*24576 + (j>>5)*1536 + (d>>4)*512 + ((j>>3)&3)*128
                    + (d&15)*8) = pk.v;
        }
        // sa/sb : tasks (tk,h)
        for (int idx = tid; idx < 8*12; idx += 512) {
            int tk = idx / 12, h = idx % 12;
            float hx = hwg[h];
            float sp = (hx > 20.f) ? hx : log1pf(__expf(hx));
            float c_pt = -0.5f * sp * CPT_K;
            float sq = 0.f, sk = 0.f;
            #pragma unroll
            for (int pp = 0; pp < 4; ++pp)
                #pragma unroll
                for (int c = 0; c < 3; ++c) {
                    float a = ldsP[tk][576 + c*48  + h*4  + pp]; sq += a*a;
                    float k = ldsP[tk][720 + c*144 + h*12 + pp]; sk += k*k;
                }
            sa_g[(b*H_+h)*N_ + n0 + tk] = c_pt * sq;
            sb_g[(b*H_+h)*N_ + n0 + tk] = c_pt * sk;
        }
    } else {
        // Qb half0 (scalar q): tasks (tk,h)
        for (int idx = tid; idx < 8*12; idx += 512) {
            int tk = idx / 12, h = idx % 12;
            union { sh8 v[2]; u16t u[16]; } pk;
            #pragma unroll
            for (int e = 0; e < 16; ++e) pk.u[e] = f2b(ldsP[tk][h*16 + e] * QSCALE);
            u16t* dst = Qb + ((b*H_+h)*N_ + n0 + tk)*32;
            *(sh8*)dst = pk.v[0];
            *(sh8*)(dst+8) = pk.v[1];
        }
        // Kp scalar frags fq in {0,1}: tasks (tk,h,fq)
        for (int idx = tid; idx < 8*24; idx += 512) {
            int tk = idx / 24, r2 = idx % 24, h = r2 >> 1, fq = r2 & 1;
            int j = n0 + tk, bh = b*H_ + h;
            union { sh8 v; u16t u[8]; } pk;
            #pragma unroll
            for (int e = 0; e < 8; ++e)
                pk.u[e] = f2b(ldsP[tk][192 + h*32 + fq*8 + e]);
            *(sh8*)(Kp + bh*16384 + (j>>4)*512 + fq*128 + (j&15)*8) = pk.v;
        }
        // Vp scalar frags d<16: tasks (h,d)
        for (int idx = tid; idx < 12*16; idx += 512) {
            int h = idx / 16, d = idx % 16;
            int bh = b*H_ + h;
            union { sh8 v; u16t u[8]; } pk;
            #pragma unroll
            for (int e = 0; e < 8; ++e)
                pk.u[e] = f2b(ldsP[e][192 + h*32 + 16 + d]);
            int j = n0;
            *(sh8*)(Vp + bh*24576 + (j>>5)*1536 + (d>>4)*512 + ((j>>3)&3)*128
                    + (d&15)*8) = pk.v;
        }
    }
}

// ---------------------------------------------------------------------------
// Kernel 2: MFMA flash attention. Block = (bh, 16-row i-tile),
// grid BH_*32 = 768 = 3 blocks/CU, 4 waves = jh 0..3 (2 jt each).
// Epilogue v2b: all 4 waves dump; waves 0-1 merge (identical order ->
// bit-identical); wave0 writes catp-o, wave1 writes obuf; point transform
// one pass over 128 threads. Barriers outside all conditionals.
// ---------------------------------------------------------------------------
__global__ __launch_bounds__(256, 3) void attn_kernel(
    const float* __restrict__ Rg, const float* __restrict__ tg,
    const float* __restrict__ maskg, float* __restrict__ ws)
{
    __shared__ u16t smP[4*16*72];     // per-wave P tiles (stride 72), 9216 B
    __shared__ float mbuf[4*64*20];   // all-wave state dumps, 20480 B
    __shared__ float obuf[16*32];     // point-coords, 2048 B

    const u16t* Qb = (const u16t*)(ws + OFF_QB);
    const u16t* Kp = (const u16t*)(ws + OFF_KP);
    const u16t* Vp = (const u16t*)(ws + OFF_VP);
    const float* sa_g = ws + OFF_SA;
    const float* sb_g = ws + OFF_SB;
    u16t* catp = (u16t*)(ws + OFF_CATP);

    const int tid  = threadIdx.x;
    const int jh   = tid >> 6, lane = tid & 63;
    const int kq   = lane >> 4, lx = lane & 15;
    const int bh   = blockIdx.x >> 5;
    const int it   = blockIdx.x & 31;
    const int b    = bh / H_, h = bh % H_;
    const int i0   = it * 16;

    sh8 qfrag = *(const sh8*)(Qb + (bh*N_ + i0 + lx)*32 + kq*8);
    float sa_r[4];
    #pragma unroll
    for (int r = 0; r < 4; ++r)
        sa_r[r] = sa_g[bh*N_ + i0 + kq*4 + r];

    float m_run[4] = {-1e30f,-1e30f,-1e30f,-1e30f};
    float l_run[4] = {0.f,0.f,0.f,0.f};
    f32x4 oc0 = {0.f,0.f,0.f,0.f}, oc1 = oc0, oc2 = oc0;

    const float* mrow = maskg + (size_t)(b*N_ + i0 + kq*4)*N_ + lx;
    u16t* pw = smP + jh*1152;

    #pragma unroll
    for (int t = 0; t < 2; ++t) {
        const int jt = jh*2 + t;
        const int j0 = jt * 64;

        f32x4 sc[4];
        #pragma unroll
        for (int st = 0; st < 4; ++st) {
            sh8 kf = *(const sh8*)(Kp + bh*16384 + (jt*4+st)*512 + kq*128 + lx*8);
            f32x4 z = {0.f,0.f,0.f,0.f};
            sc[st] = __builtin_amdgcn_mfma_f32_16x16x32_bf16(qfrag, kf, z, 0, 0, 0);
        }
        float sbv[4];
        #pragma unroll
        for (int st = 0; st < 4; ++st) sbv[st] = sb_g[bh*N_ + j0 + st*16 + lx];
        float mb[16];
        #pragma unroll
        for (int r = 0; r < 4; ++r)
            #pragma unroll
            for (int st = 0; st < 4; ++st)
                mb[r*4+st] = mrow[r*N_ + j0 + st*16];

        float L[16];
        #pragma unroll
        for (int st = 0; st < 4; ++st)
            #pragma unroll
            for (int r = 0; r < 4; ++r)
                L[st*4+r] = sc[st][r] + sa_r[r] + sbv[st] + 1e5f*(mb[r*4+st] - 1.f);

        #pragma unroll
        for (int r = 0; r < 4; ++r) {
            float tm = fmaxf(fmaxf(L[0*4+r], L[1*4+r]), fmaxf(L[2*4+r], L[3*4+r]));
            tm = fmaxf(tm, __shfl_xor(tm, 1));
            tm = fmaxf(tm, __shfl_xor(tm, 2));
            tm = fmaxf(tm, __shfl_xor(tm, 4));
            tm = fmaxf(tm, __shfl_xor(tm, 8));
            float mnew = fmaxf(m_run[r], tm);
            float al = __expf(m_run[r] - mnew);
            m_run[r] = mnew;
            l_run[r] *= al;
            oc0[r] *= al; oc1[r] *= al; oc2[r] *= al;
        }
        #pragma unroll
        for (int st = 0; st < 4; ++st)
            #pragma unroll
            for (int r = 0; r < 4; ++r) {
                float p = __expf(L[st*4+r] - m_run[r]);
                l_run[r] += p;
                pw[(kq*4+r)*72 + st*16 + lx] = f2b(p);
            }
        #pragma unroll
        for (int c = 0; c < 2; ++c) {
            sh8 pa = *(const sh8*)(pw + lx*72 + c*32 + kq*8);
            #pragma unroll
            for (int nq = 0; nq < 3; ++nq) {
                sh8 vf = *(const sh8*)(Vp + bh*24576 + (jt*2+c)*1536 + nq*512
                                        + kq*128 + lx*8);
                if (nq == 0) oc0 = __builtin_amdgcn_mfma_f32_16x16x32_bf16(pa, vf, oc0, 0,0,0);
                if (nq == 1) oc1 = __builtin_amdgcn_mfma_f32_16x16x32_bf16(pa, vf, oc1, 0,0,0);
                if (nq == 2) oc2 = __builtin_amdgcn_mfma_f32_16x16x32_bf16(pa, vf, oc2, 0,0,0);
            }
        }
    }

    // all waves dump state
    {
        float* mb = mbuf + (jh*64 + lane)*20;
        #pragma unroll
        for (int r = 0; r < 4; ++r) {
            mb[r]      = m_run[r];
            mb[4 + r]  = l_run[r];
            mb[8 + r]  = oc0[r];
            mb[12 + r] = oc1[r];
            mb[16 + r] = oc2[r];
        }
    }
    __syncthreads();

    // waves 0-1 merge all 4 states (identical order q=0..3 -> bit-identical)
    if (jh < 2) {
        float linv[4];
        f32x4 mo0, mo1, mo2;
        #pragma unroll
        for (int r = 0; r < 4; ++r) {
            float ms = -1e30f;
            #pragma unroll
            for (int q = 0; q < 4; ++q)
                ms = fmaxf(ms, mbuf[(q*64 + lane)*20 + r]);
            float l = 0.f, o0 = 0.f, o1 = 0.f, o2 = 0.f;
            #pragma unroll
            for (int q = 0; q < 4; ++q) {
                const float* mb = mbuf + (q*64 + lane)*20;
                float e = __expf(mb[r] - ms);
                l  += mb[4 + r]*e;
                o0 += mb[8 + r]*e;
                o1 += mb[12 + r]*e;
                o2 += mb[16 + r]*e;
            }
            l += __shfl_xor(l, 1); l += __shfl_xor(l, 2);
            l += __shfl_xor(l, 4); l += __shfl_xor(l, 8);
            linv[r] = 1.f / l;
            mo0[r] = o0; mo1[r] = o1; mo2[r] = o2;
        }

        if (jh == 0) {             // o part -> CAT-packed (bf16)
            #pragma unroll
            for (int r = 0; r < 4; ++r) {
                int tok = b*N_ + i0 + kq*4 + r;
                catp[catp_idx(tok, h*16 + lx)] = f2b(mo0[r] * linv[r]);
            }
        } else {                   // point-coords -> obuf
            #pragma unroll
            for (int r = 0; r < 4; ++r) {
                int row = kq*4 + r;
                obuf[row*32 + lx]      = mo1[r] * linv[r];
                obuf[row*32 + 16 + lx] = mo2[r] * linv[r];
            }
        }
    }
    __syncthreads();

    // points: R^T g - t, norm; 128 tasks in ONE pass over waves 0-1
    if (tid < 128) {
        int r = tid >> 3, pv = tid & 7;
        int tok = b*N_ + i0 + r;
        const float* Rr = Rg + tok*9;
        const float* tr = tg + tok*3;
        float g0 = obuf[r*32 + pv*3 + 0];
        float g1 = obuf[r*32 + pv*3 + 1];
        float g2 = obuf[r*32 + pv*3 + 2];
        float px = Rr[0]*g0 + Rr[3]*g1 + Rr[6]*g2 - tr[0];
        float py = Rr[1]*g0 + Rr[4]*g1 + Rr[7]*g2 - tr[1];
        float pz = Rr[2]*g0 + Rr[5]*g1 + Rr[8]*g2 - tr[2];
        float nrm = sqrtf(px*px + py*py + pz*pz + 1e-8f);
        catp[catp_idx(tok, 192 + h*8 + pv)] = f2b(px);
        catp[catp_idx(tok, 288 + h*8 + pv)] = f2b(py);
        catp[catp_idx(tok, 384 + h*8 + pv)] = f2b(pz);
        catp[catp_idx(tok, 480 + h*8 + pv)] = f2b(nrm);
    }
}

// ---------------------------------------------------------------------------
// Kernel 3: out GEMM, 8-way split-K, Wout packed on the fly.
// grid (8 nt16, 64 mt) = 512 blocks (2/CU) x 512. Wave kh = w covers
// ks in [kh*18/8,(kh+1)*18/8) -> 2-3 dependent MFMAs. 7-partial LDS merge.
// ---------------------------------------------------------------------------
__global__ __launch_bounds__(512) void out_kernel(
    const float* __restrict__ Wout, const float* __restrict__ bout,
    const float* __restrict__ ws, float* __restrict__ out)
{
    __shared__ float part[7][64][4];

    const int tid = threadIdx.x;
    const int kh = tid >> 6, lane = tid & 63;
    const int lx = lane & 15, kq = lane >> 4;
    const int nt = blockIdx.x, mt = blockIdx.y;

    const sh8* Ap = (const sh8*)((const u16t*)(ws + OFF_CATP));

    const int col = nt*16 + lx;
    const int ke0 = (kh*18) >> 3;          // {0,2,4,6,9,11,13,15}
    const int ke1 = ((kh+1)*18) >> 3;      // {2,4,6,9,11,13,15,18}

    f32x4 acc = {0.f,0.f,0.f,0.f};
    #pragma unroll 3
    for (int ks = ke0; ks < ke1; ++ks) {
        sh8 af = Ap[((mt*18 + ks)*4 + kq)*16 + lx];
        int k0 = ks*32 + kq*8;
        union { sh8 v; u16t u[8]; } pk;
        #pragma unroll
        for (int j = 0; j < 8; ++j) pk.u[j] = f2b(Wout[(k0+j)*128 + col]);
        acc = __builtin_amdgcn_mfma_f32_16x16x32_bf16(af, pk.v, acc, 0, 0, 0);
    }
    if (kh > 0) {
        #pragma unroll
        for (int r = 0; r < 4; ++r) part[kh-1][lane][r] = acc[r];
    }
    __syncthreads();
    if (kh == 0) {
        float bv = bout[col];
        #pragma unroll
        for (int r = 0; r < 4; ++r) {
            float v = acc[r];
            #pragma unroll
            for (int p = 0; p < 7; ++p) v += part[p][lane][r];
            int row = mt*16 + kq*4 + r;
            out[row*128 + col] = v + bv;
        }
    }
}

extern "C" void kernel_launch(void* const* d_in, const int* in_sizes, int n_in,
                              void* d_out, int out_size, void* d_ws, size_t ws_size,
                              hipStream_t stream) {
    const float* s    = (const float*)d_in[0];
    const float* R    = (const float*)d_in[1];
    const float* t    = (const float*)d_in[2];
    const float* mask = (const float*)d_in[3];
    const float* Wq   = (const float*)d_in[4];
    const float* bq   = (const float*)d_in[5];
    const float* Wkv  = (const float*)d_in[6];
    const float* bkv  = (const float*)d_in[7];
    const float* Wqp  = (const float*)d_in[8];
    const float* bqp  = (const float*)d_in[9];
    const float* Wkvp = (const float*)d_in[10];
    const float* bkvp = (const float*)d_in[11];
    const float* hw   = (const float*)d_in[12];
    const float* Wout = (const float*)d_in[13];
    const float* bout = (const float*)d_in[14];
    float* ws  = (float*)d_ws;
    float* out = (float*)d_out;

    projpack_kernel<<<256, 512, 0, stream>>>(s, R, t, hw, Wq, bq, Wkv, bkv,
                                             Wqp, bqp, Wkvp, bkvp, ws);
    attn_kernel<<<BH_*32, 256, 0, stream>>>(R, t, mask, ws);
    out_kernel<<<dim3(8, 64), 512, 0, stream>>>(Wout, bout, ws, out);
}

// Round 8
// 105.621 us; speedup vs baseline: 1.0253x; 1.0253x over previous
//
#include <hip/hip_runtime.h>
#include <hip/hip_bf16.h>
#include <math.h>

#define H_    12
#define B_    2
#define N_    512
#define BH_   (B_*H_)
#define QSCALE 0.14433756729740643f          // 1/sqrt(48)
#define CPT_K  0.13608276348795434f          // sqrt(1/54)

// ---------------- ws layout (float units) ----------------
#define OFF_QB   1356928                     // bf16 [bh][512][32]
#define OFF_KP   1553536                     // bf16 [bh][32jt][4kq][16j][8]
#define OFF_VP   1750144                     // bf16 [bh][16jt32][3nq][4kq][16n][8j]
#define OFF_SA   2045056                     // f32 [bh*512]
#define OFF_SB   2057344                     // f32 [bh*512]
#define OFF_CATP 2069632                     // bf16 [64mt][18ks][4kq][16m][8]

typedef __attribute__((ext_vector_type(8))) short sh8;
typedef __attribute__((ext_vector_type(4))) float f32x4;
typedef unsigned short u16t;

static __device__ __forceinline__ u16t f2b(float x) {
    __hip_bfloat16 h = __float2bfloat16(x);
    return *reinterpret_cast<u16t*>(&h);
}
static __device__ __forceinline__ int catp_idx(int tok, int col) {
    return (tok >> 4)*9216 + (col >> 5)*512 + ((col >> 3) & 3)*128
         + (tok & 15)*8 + (col & 7);
}

// ---------------------------------------------------------------------------
// Kernel 1: fused proj GEMM + rotation + bf16 pack, half-column split.
// Grid 256 (= 1 block/CU): bid>>1 = 8-token group, bid&1 = column half.
// ---------------------------------------------------------------------------
__global__ __launch_bounds__(512) void projpack_kernel(
    const float* __restrict__ s,
    const float* __restrict__ Rg, const float* __restrict__ tg,
    const float* __restrict__ hwg,
    const float* __restrict__ Wq,  const float* __restrict__ bq,
    const float* __restrict__ Wkv, const float* __restrict__ bkv,
    const float* __restrict__ Wqp, const float* __restrict__ bqp,
    const float* __restrict__ Wkvp,const float* __restrict__ bkvp,
    float* __restrict__ ws)
{
    __shared__ float ldsP[8][1160];   // 8 tokens x 1152 (+8 pad); half-used/block

    u16t* Qb = (u16t*)(ws + OFF_QB);
    u16t* Kp = (u16t*)(ws + OFF_KP);
    u16t* Vp = (u16t*)(ws + OFF_VP);
    float* sa_g = ws + OFF_SA;
    float* sb_g = ws + OFF_SB;

    const int tid  = threadIdx.x;
    const int w    = tid >> 6, lane = tid & 63;
    const int kq   = lane >> 4, lx = lane & 15;
    const int half = blockIdx.x & 1;
    const int tok0 = (blockIdx.x >> 1) * 8;
    const int b    = tok0 >> 9, n0 = tok0 & 511;

    // A-frags: s rows tok0 + (lx&7), k = ks*32 + kq*8 .. +8
    sh8 afr[4];
    #pragma unroll
    for (int ks = 0; ks < 4; ++ks) {
        const float* src = s + (tok0 + (lx & 7))*128 + ks*32 + kq*8;
        float4 u0 = *(const float4*)(src);
        float4 u1 = *(const float4*)(src+4);
        union { sh8 v; u16t u[8]; } pk;
        pk.u[0]=f2b(u0.x); pk.u[1]=f2b(u0.y); pk.u[2]=f2b(u0.z); pk.u[3]=f2b(u0.w);
        pk.u[4]=f2b(u1.x); pk.u[5]=f2b(u1.y); pk.u[6]=f2b(u1.z); pk.u[7]=f2b(u1.w);
        afr[ks] = pk.v;
    }

    const int gstart = (w < 4) ? w*5 : 20 + (w-4)*4;
    const int ng     = (w < 4) ? 5 : 4;

    for (int g = 0; g < ng; ++g) {
        int gg  = half*36 + gstart + g;    // global col-group 0..71
        int col = gg*16 + lx;              // each 16-col group maps to ONE matrix
        const float* wsrc; int lc, od; float bv;
        if (col < 192)      { wsrc = Wq;   lc = col;     od = 192; bv = bq[lc]; }
        else if (col < 576) { wsrc = Wkv;  lc = col-192; od = 384; bv = bkv[lc]; }
        else if (col < 720) { wsrc = Wqp;  lc = col-576; od = 144; bv = bqp[lc]; }
        else                { wsrc = Wkvp; lc = col-720; od = 432; bv = bkvp[lc]; }

        f32x4 acc = {0.f,0.f,0.f,0.f};
        #pragma unroll
        for (int ks = 0; ks < 4; ++ks) {
            int k0 = ks*32 + kq*8;
            union { sh8 v; u16t u[8]; } pk;
            #pragma unroll
            for (int j = 0; j < 8; ++j) pk.u[j] = f2b(wsrc[(k0+j)*od + lc]);
            acc = __builtin_amdgcn_mfma_f32_16x16x32_bf16(afr[ks], pk.v, acc, 0, 0, 0);
        }
        if (kq < 2) {                      // C rows 0..7 only
            #pragma unroll
            for (int r = 0; r < 4; ++r)
                ldsP[kq*4 + r][gg*16 + lx] = acc[r] + bv;
        }
    }
    __syncthreads();

    if (half == 1) {
        // in-place rotation: qp (cols 576..720)
        for (int idx = tid; idx < 8*48; idx += 512) {
            int tk = idx / 48, p = idx % 48;
            int tok = tok0 + tk;
            const float* Rr = Rg + tok*9;
            const float* tr = tg + tok*3;
            float x0 = ldsP[tk][576 +  0 + p];
            float x1 = ldsP[tk][576 + 48 + p];
            float x2 = ldsP[tk][576 + 96 + p];
            ldsP[tk][576 +  0 + p] = Rr[0]*x0 + Rr[1]*x1 + Rr[2]*x2 + tr[0];
            ldsP[tk][576 + 48 + p] = Rr[3]*x0 + Rr[4]*x1 + Rr[5]*x2 + tr[1];
            ldsP[tk][576 + 96 + p] = Rr[6]*x0 + Rr[7]*x1 + Rr[8]*x2 + tr[2];
        }
        // in-place rotation: kvp (cols 720..1152)
        for (int idx = tid; idx < 8*144; idx += 512) {
            int tk = idx / 144, p = idx % 144;
            int tok = tok0 + tk;
            const float* Rr = Rg + tok*9;
            const float* tr = tg + tok*3;
            float x0 = ldsP[tk][720 +   0 + p];
            float x1 = ldsP[tk][720 + 144 + p];
            float x2 = ldsP[tk][720 + 288 + p];
            ldsP[tk][720 +   0 + p] = Rr[0]*x0 + Rr[1]*x1 + Rr[2]*x2 + tr[0];
            ldsP[tk][720 + 144 + p] = Rr[3]*x0 + Rr[4]*x1 + Rr[5]*x2 + tr[1];
            ldsP[tk][720 + 288 + p] = Rr[6]*x0 + Rr[7]*x1 + Rr[8]*x2 + tr[2];
        }
        __syncthreads();

        // Qb half1 (point part): tasks (tk,h)
        for (int idx = tid; idx < 8*12; idx += 512) {
            int tk = idx / 12, h = idx % 12;
            float hx = hwg[h];
            float sp = (hx > 20.f) ? hx : log1pf(__expf(hx));
            float qs = sp * CPT_K;         // = -2 * c_pt
            union { sh8 v[2]; u16t u[16]; } pk;
            #pragma unroll
            for (int e = 0; e < 12; ++e)
                pk.u[e] = f2b(ldsP[tk][576 + (e%3)*48 + h*4 + e/3] * qs);
            pk.u[12]=0; pk.u[13]=0; pk.u[14]=0; pk.u[15]=0;
            u16t* dst = Qb + ((b*H_+h)*N_ + n0 + tk)*32 + 16;
            *(sh8*)dst = pk.v[0];
            *(sh8*)(dst+8) = pk.v[1];
        }
        // Kp point frags fq in {2,3}: tasks (tk,h,fq)
        for (int idx = tid; idx < 8*24; idx += 512) {
            int tk = idx / 24, r2 = idx % 24, h = r2 >> 1, fq = 2 + (r2 & 1);
            int j = n0 + tk, bh = b*H_ + h;
            union { sh8 v; u16t u[8]; } pk;
            #pragma unroll
            for (int e = 0; e < 8; ++e) {
                int c = fq*8 + e;
                float val;
                if (c < 28) val = ldsP[tk][720 + ((c-16)%3)*144 + h*12 + (c-16)/3];
                else        val = 0.f;
                pk.u[e] = f2b(val);
            }
            *(sh8*)(Kp + bh*16384 + (j>>4)*512 + fq*128 + (j&15)*8) = pk.v;
        }
        // Vp point frags d in [16,40): tasks (h,d-16)
        for (int idx = tid; idx < 12*24; idx += 512) {
            int h = idx / 24, d = 16 + idx % 24;
            int bh = b*H_ + h;
            union { sh8 v; u16t u[8]; } pk;
            #pragma unroll
            for (int e = 0; e < 8; ++e)
                pk.u[e] = f2b(ldsP[e][720 + ((d-16)%3)*144 + h*12 + 4 + (d-16)/3]);
            int j = n0;
            *(sh8*)(Vp + bh*24576 + (j>>5)*1536 + (d>>4)*512 + ((j>>3)&3)*128
                    + (d&15)*8) = pk.v;
        }
        // sa/sb : tasks (tk,h)
        for (int idx = tid; idx < 8*12; idx += 512) {
            int tk = idx / 12, h = idx % 12;
            float hx = hwg[h];
            float sp = (hx > 20.f) ? hx : log1pf(__expf(hx));
            float c_pt = -0.5f * sp * CPT_K;
            float sq = 0.f, sk = 0.f;
            #pragma unroll
            for (int pp = 0; pp < 4; ++pp)
                #pragma unroll
                for (int c = 0; c < 3; ++c) {
                    float a = ldsP[tk][576 + c*48  + h*4  + pp]; sq += a*a;
                    float k = ldsP[tk][720 + c*144 + h*12 + pp]; sk += k*k;
                }
            sa_g[(b*H_+h)*N_ + n0 + tk] = c_pt * sq;
            sb_g[(b*H_+h)*N_ + n0 + tk] = c_pt * sk;
        }
    } else {
        // Qb half0 (scalar q): tasks (tk,h)
        for (int idx = tid; idx < 8*12; idx += 512) {
            int tk = idx / 12, h = idx % 12;
            union { sh8 v[2]; u16t u[16]; } pk;
            #pragma unroll
            for (int e = 0; e < 16; ++e) pk.u[e] = f2b(ldsP[tk][h*16 + e] * QSCALE);
            u16t* dst = Qb + ((b*H_+h)*N_ + n0 + tk)*32;
            *(sh8*)dst = pk.v[0];
            *(sh8*)(dst+8) = pk.v[1];
        }
        // Kp scalar frags fq in {0,1}: tasks (tk,h,fq)
        for (int idx = tid; idx < 8*24; idx += 512) {
            int tk = idx / 24, r2 = idx % 24, h = r2 >> 1, fq = r2 & 1;
            int j = n0 + tk, bh = b*H_ + h;
            union { sh8 v; u16t u[8]; } pk;
            #pragma unroll
            for (int e = 0; e < 8; ++e)
                pk.u[e] = f2b(ldsP[tk][192 + h*32 + fq*8 + e]);
            *(sh8*)(Kp + bh*16384 + (j>>4)*512 + fq*128 + (j&15)*8) = pk.v;
        }
        // Vp scalar frags d<16: tasks (h,d)
        for (int idx = tid; idx < 12*16; idx += 512) {
            int h = idx / 16, d = idx % 16;
            int bh = b*H_ + h;
            union { sh8 v; u16t u[8]; } pk;
            #pragma unroll
            for (int e = 0; e < 8; ++e)
                pk.u[e] = f2b(ldsP[e][192 + h*32 + 16 + d]);
            int j = n0;
            *(sh8*)(Vp + bh*24576 + (j>>5)*1536 + (d>>4)*512 + ((j>>3)&3)*128
                    + (d&15)*8) = pk.v;
        }
    }
}

// ---------------------------------------------------------------------------
// Kernel 2: MFMA flash attention, rebalanced. Block = (bh, 16-row i-tile),
// grid BH_*32 = 768 = exactly 3 blocks/CU, 4 waves = jh 0..3 (2 jt each).
// 4-way online-softmax merge across the 4 waves via LDS.
// ---------------------------------------------------------------------------
__global__ __launch_bounds__(256, 3) void attn_kernel(
    const float* __restrict__ Rg, const float* __restrict__ tg,
    const float* __restrict__ maskg, float* __restrict__ ws)
{
    __shared__ u16t smP[4*16*72];     // per-wave P tiles (stride 72), 9216 B
    __shared__ float mbuf[3*64*20];   // jh=1..3 state dumps, 15360 B
    __shared__ float obuf[16*32];     // point-coords, 2048 B

    const u16t* Qb = (const u16t*)(ws + OFF_QB);
    const u16t* Kp = (const u16t*)(ws + OFF_KP);
    const u16t* Vp = (const u16t*)(ws + OFF_VP);
    const float* sa_g = ws + OFF_SA;
    const float* sb_g = ws + OFF_SB;
    u16t* catp = (u16t*)(ws + OFF_CATP);

    const int tid  = threadIdx.x;
    const int jh   = tid >> 6, lane = tid & 63;
    const int kq   = lane >> 4, lx = lane & 15;
    const int bh   = blockIdx.x >> 5;
    const int it   = blockIdx.x & 31;
    const int b    = bh / H_, h = bh % H_;
    const int i0   = it * 16;

    sh8 qfrag = *(const sh8*)(Qb + (bh*N_ + i0 + lx)*32 + kq*8);
    float sa_r[4];
    #pragma unroll
    for (int r = 0; r < 4; ++r)
        sa_r[r] = sa_g[bh*N_ + i0 + kq*4 + r];

    float m_run[4] = {-1e30f,-1e30f,-1e30f,-1e30f};
    float l_run[4] = {0.f,0.f,0.f,0.f};
    f32x4 oc0 = {0.f,0.f,0.f,0.f}, oc1 = oc0, oc2 = oc0;

    const float* mrow = maskg + (size_t)(b*N_ + i0 + kq*4)*N_ + lx;
    u16t* pw = smP + jh*1152;

    #pragma unroll
    for (int t = 0; t < 2; ++t) {
        const int jt = jh*2 + t;
        const int j0 = jt * 64;

        f32x4 sc[4];
        #pragma unroll
        for (int st = 0; st < 4; ++st) {
            sh8 kf = *(const sh8*)(Kp + bh*16384 + (jt*4+st)*512 + kq*128 + lx*8);
            f32x4 z = {0.f,0.f,0.f,0.f};
            sc[st] = __builtin_amdgcn_mfma_f32_16x16x32_bf16(qfrag, kf, z, 0, 0, 0);
        }
        float sbv[4];
        #pragma unroll
        for (int st = 0; st < 4; ++st) sbv[st] = sb_g[bh*N_ + j0 + st*16 + lx];
        float mb[16];
        #pragma unroll
        for (int r = 0; r < 4; ++r)
            #pragma unroll
            for (int st = 0; st < 4; ++st)
                mb[r*4+st] = mrow[r*N_ + j0 + st*16];

        float L[16];
        #pragma unroll
        for (int st = 0; st < 4; ++st)
            #pragma unroll
            for (int r = 0; r < 4; ++r)
                L[st*4+r] = sc[st][r] + sa_r[r] + sbv[st] + 1e5f*(mb[r*4+st] - 1.f);

        #pragma unroll
        for (int r = 0; r < 4; ++r) {
            float tm = fmaxf(fmaxf(L[0*4+r], L[1*4+r]), fmaxf(L[2*4+r], L[3*4+r]));
            tm = fmaxf(tm, __shfl_xor(tm, 1));
            tm = fmaxf(tm, __shfl_xor(tm, 2));
            tm = fmaxf(tm, __shfl_xor(tm, 4));
            tm = fmaxf(tm, __shfl_xor(tm, 8));
            float mnew = fmaxf(m_run[r], tm);
            float al = __expf(m_run[r] - mnew);
            m_run[r] = mnew;
            l_run[r] *= al;
            oc0[r] *= al; oc1[r] *= al; oc2[r] *= al;
        }
        #pragma unroll
        for (int st = 0; st < 4; ++st)
            #pragma unroll
            for (int r = 0; r < 4; ++r) {
                float p = __expf(L[st*4+r] - m_run[r]);
                l_run[r] += p;
                pw[(kq*4+r)*72 + st*16 + lx] = f2b(p);
            }
        #pragma unroll
        for (int c = 0; c < 2; ++c) {
            sh8 pa = *(const sh8*)(pw + lx*72 + c*32 + kq*8);
            #pragma unroll
            for (int nq = 0; nq < 3; ++nq) {
                sh8 vf = *(const sh8*)(Vp + bh*24576 + (jt*2+c)*1536 + nq*512
                                        + kq*128 + lx*8);
                if (nq == 0) oc0 = __builtin_amdgcn_mfma_f32_16x16x32_bf16(pa, vf, oc0, 0,0,0);
                if (nq == 1) oc1 = __builtin_amdgcn_mfma_f32_16x16x32_bf16(pa, vf, oc1, 0,0,0);
                if (nq == 2) oc2 = __builtin_amdgcn_mfma_f32_16x16x32_bf16(pa, vf, oc2, 0,0,0);
            }
        }
    }

    // dump jh>0 states
    if (jh > 0) {
        float* mb = mbuf + ((jh-1)*64 + lane)*20;
        #pragma unroll
        for (int r = 0; r < 4; ++r) {
            mb[r]      = m_run[r];
            mb[4 + r]  = l_run[r];
            mb[8 + r]  = oc0[r];
            mb[12 + r] = oc1[r];
            mb[16 + r] = oc2[r];
        }
    }
    __syncthreads();
    if (jh == 0) {
        float linv[4];
        #pragma unroll
        for (int r = 0; r < 4; ++r) {
            float ms = m_run[r];
            #pragma unroll
            for (int q = 0; q < 3; ++q)
                ms = fmaxf(ms, mbuf[(q*64 + lane)*20 + r]);
            float eA = __expf(m_run[r] - ms);
            float l = l_run[r]*eA;
            oc0[r] *= eA; oc1[r] *= eA; oc2[r] *= eA;
            #pragma unroll
            for (int q = 0; q < 3; ++q) {
                const float* mb = mbuf + (q*64 + lane)*20;
                float e = __expf(mb[r] - ms);
                l      += mb[4+r]*e;
                oc0[r] += mb[8+r]*e;
                oc1[r] += mb[12+r]*e;
                oc2[r] += mb[16+r]*e;
            }
            l += __shfl_xor(l, 1); l += __shfl_xor(l, 2);
            l += __shfl_xor(l, 4); l += __shfl_xor(l, 8);
            linv[r] = 1.f / l;
        }

        // o part -> CAT-packed (bf16), points -> obuf
        #pragma unroll
        for (int r = 0; r < 4; ++r) {
            int row = kq*4 + r;
            int tok = b*N_ + i0 + row;
            catp[catp_idx(tok, h*16 + lx)] = f2b(oc0[r] * linv[r]);
            obuf[row*32 + lx]      = oc1[r] * linv[r];
            obuf[row*32 + 16 + lx] = oc2[r] * linv[r];
        }

        // points: R^T g - t, norm; 16 rows x 8 pts = 128 tasks over 2 passes
        #pragma unroll
        for (int tsk = 0; tsk < 2; ++tsk) {
            int task = lane + tsk*64;
            int r = task >> 3, pv = task & 7;
            int tok = b*N_ + i0 + r;
            const float* Rr = Rg + tok*9;
            const float* tr = tg + tok*3;
            float g0 = obuf[r*32 + pv*3 + 0];
            float g1 = obuf[r*32 + pv*3 + 1];
            float g2 = obuf[r*32 + pv*3 + 2];
            float px = Rr[0]*g0 + Rr[3]*g1 + Rr[6]*g2 - tr[0];
            float py = Rr[1]*g0 + Rr[4]*g1 + Rr[7]*g2 - tr[1];
            float pz = Rr[2]*g0 + Rr[5]*g1 + Rr[8]*g2 - tr[2];
            float nrm = sqrtf(px*px + py*py + pz*pz + 1e-8f);
            catp[catp_idx(tok, 192 + h*8 + pv)] = f2b(px);
            catp[catp_idx(tok, 288 + h*8 + pv)] = f2b(py);
            catp[catp_idx(tok, 384 + h*8 + pv)] = f2b(pz);
            catp[catp_idx(tok, 480 + h*8 + pv)] = f2b(nrm);
        }
    }
}

// ---------------------------------------------------------------------------
// Kernel 3: out GEMM, 4-way split-K, Wout packed on the fly.
// grid (4 nt32, 64 mt) = 256 blocks x 512.
// ---------------------------------------------------------------------------
__global__ __launch_bounds__(512) void out_kernel(
    const float* __restrict__ Wout, const float* __restrict__ bout,
    const float* __restrict__ ws, float* __restrict__ out)
{
    __shared__ float part[2][3][64][4];

    const int tid = threadIdx.x;
    const int w = tid >> 6, lane = tid & 63;
    const int cg = w & 1, kh = w >> 1;
    const int lx = lane & 15, kq = lane >> 4;
    const int nt = blockIdx.x, mt = blockIdx.y;

    const sh8* Ap = (const sh8*)((const u16t*)(ws + OFF_CATP));

    const int col = nt*32 + cg*16 + lx;
    const int ke0 = (kh*18) >> 2;          // {0,4,9,13}
    const int ke1 = ((kh+1)*18) >> 2;      // {4,9,13,18}

    f32x4 acc = {0.f,0.f,0.f,0.f};
    #pragma unroll 5
    for (int ks = ke0; ks < ke1; ++ks) {
        sh8 af = Ap[((mt*18 + ks)*4 + kq)*16 + lx];
        int k0 = ks*32 + kq*8;
        union { sh8 v; u16t u[8]; } pk;
        #pragma unroll
        for (int j = 0; j < 8; ++j) pk.u[j] = f2b(Wout[(k0+j)*128 + col]);
        acc = __builtin_amdgcn_mfma_f32_16x16x32_bf16(af, pk.v, acc, 0, 0, 0);
    }
    if (kh > 0) {
        #pragma unroll
        for (int r = 0; r < 4; ++r) part[cg][kh-1][lane][r] = acc[r];
    }
    __syncthreads();
    if (kh == 0) {
        float bv = bout[col];
        #pragma unroll
        for (int r = 0; r < 4; ++r) {
            int row = mt*16 + kq*4 + r;
            out[row*128 + col] = acc[r] + part[cg][0][lane][r]
                               + part[cg][1][lane][r] + part[cg][2][lane][r] + bv;
        }
    }
}

extern "C" void kernel_launch(void* const* d_in, const int* in_sizes, int n_in,
                              void* d_out, int out_size, void* d_ws, size_t ws_size,
                              hipStream_t stream) {
    const float* s    = (const float*)d_in[0];
    const float* R    = (const float*)d_in[1];
    const float* t    = (const float*)d_in[2];
    const float* mask = (const float*)d_in[3];
    const float* Wq   = (const float*)d_in[4];
    const float* bq   = (const float*)d_in[5];
    const float* Wkv  = (const float*)d_in[6];
    const float* bkv  = (const float*)d_in[7];
    const float* Wqp  = (const float*)d_in[8];
    const float* bqp  = (const float*)d_in[9];
    const float* Wkvp = (const float*)d_in[10];
    const float* bkvp = (const float*)d_in[11];
    const float* hw   = (const float*)d_in[12];
    const float* Wout = (const float*)d_in[13];
    const float* bout = (const float*)d_in[14];
    float* ws  = (float*)d_ws;
    float* out = (float*)d_out;

    projpack_kernel<<<256, 512, 0, stream>>>(s, R, t, hw, Wq, bq, Wkv, bkv,
                                             Wqp, bqp, Wkvp, bkvp, ws);
    attn_kernel<<<BH_*32, 256, 0, stream>>>(R, t, mask, ws);
    out_kernel<<<dim3(4, 64), 512, 0, stream>>>(Wout, bout, ws, out);
}